// Round 18
// baseline (1493.706 us; speedup 1.0000x reference)
//
#include <hip/hip_runtime.h>

typedef __attribute__((ext_vector_type(8))) short short8;
typedef __attribute__((ext_vector_type(4))) short short4v;
typedef __attribute__((ext_vector_type(4))) float f32x4;

__device__ __forceinline__ unsigned short f2bf(float f) {
  union { float f; unsigned u; } v; v.f = f;
  unsigned r = v.u + 0x7FFFu + ((v.u >> 16) & 1u);
  return (unsigned short)(r >> 16);
}

__device__ __forceinline__ float bf2f(unsigned short h) {
  union { unsigned u; float f; } v; v.u = ((unsigned)h) << 16;
  return v.f;
}

__device__ __forceinline__ void gload16(const void* g, void* l) {
  __builtin_amdgcn_global_load_lds(
      (const __attribute__((address_space(1))) void*)g,
      (__attribute__((address_space(3))) void*)l, 16, 0, 0);
}

// ---------------------------------------------------------------------------
// Kernel 0: x (fp32) -> x_bf16, vectorized 8 elems/thread
// ---------------------------------------------------------------------------
__global__ __launch_bounds__(256) void conv_x(const float* __restrict__ x,
                                              unsigned short* __restrict__ xb) {
  const long total = 25165824;                        // 201326592 / 8
  long stride = (long)gridDim.x * 256;
  for (long u = blockIdx.x * 256 + threadIdx.x; u < total; u += stride) {
    const float* p = x + u * 8;
    float4 a = *(const float4*)p;
    float4 b = *(const float4*)(p + 4);
    short8 h;
    h[0] = (short)f2bf(a.x); h[1] = (short)f2bf(a.y);
    h[2] = (short)f2bf(a.z); h[3] = (short)f2bf(a.w);
    h[4] = (short)f2bf(b.x); h[5] = (short)f2bf(b.y);
    h[6] = (short)f2bf(b.z); h[7] = (short)f2bf(b.w);
    *(short8*)(xb + u * 8) = h;
  }
}

// ---------------------------------------------------------------------------
// Kernel 1: Wt[n][k] = bf16( [Wk | Wv](k, n) )   (B^T layout, n in [0,1536))
// ---------------------------------------------------------------------------
__global__ __launch_bounds__(256) void prep_w(const float* __restrict__ Wk,
                                              const float* __restrict__ Wv,
                                              unsigned short* __restrict__ Wt) {
  int idx = blockIdx.x * 256 + threadIdx.x;           // 1536*768 elements
  int n = idx / 768, k = idx - n * 768;
  float w = (n < 768) ? Wk[k * 768 + n] : Wv[k * 768 + (n - 768)];
  Wt[idx] = f2bf(w);
}

// ---------------------------------------------------------------------------
// Kernel 2: q = scale * x[:, :10] @ Wq  -> q_ws[b][h][16][64] bf16 (rows 10..15 = 0)
// ---------------------------------------------------------------------------
__global__ __launch_bounds__(256) void q_proj(const float* __restrict__ x,
                                              const float* __restrict__ Wq,
                                              unsigned short* __restrict__ q_ws) {
  int b = blockIdx.x, tid = threadIdx.x;
  __shared__ float xr[7680];
  const float* xp = x + (long)b * 4096 * 768;
  for (int i = tid; i < 7680; i += 256) xr[i] = xp[i];
  for (int i = tid; i < 12 * 6 * 64; i += 256) {
    int h = i / 384, rem = i - h * 384;
    int t = 10 + rem / 64, d = rem & 63;
    q_ws[(((long)(b * 12 + h) * 16 + t) << 6) + d] = 0;
  }
  __syncthreads();
  float acc[10][3];
#pragma unroll
  for (int t = 0; t < 10; ++t) { acc[t][0] = 0.f; acc[t][1] = 0.f; acc[t][2] = 0.f; }
  for (int k = 0; k < 768; ++k) {
    const float* wr = Wq + (long)k * 768;
    float w0 = wr[tid], w1 = wr[tid + 256], w2 = wr[tid + 512];
#pragma unroll
    for (int t = 0; t < 10; ++t) {
      float xv = xr[t * 768 + k];
      acc[t][0] += xv * w0; acc[t][1] += xv * w1; acc[t][2] += xv * w2;
    }
  }
#pragma unroll
  for (int t = 0; t < 10; ++t) {
#pragma unroll
    for (int j = 0; j < 3; ++j) {
      int c = tid + j * 256;
      int h = c >> 6, d = c & 63;
      q_ws[(((long)(b * 12 + h) * 16 + t) << 6) + d] = f2bf(acc[t][j] * 0.125f);
    }
  }
}

// ---------------------------------------------------------------------------
// Shared macros for the 256x256 BK=64 4-phase GEMM core (R8/R10 proven)
// ---------------------------------------------------------------------------
#define SGA(AT, I, KO) gload16(sA + (long)(I) * 49152 + (KO), (AT) + ((I) * 64 + uw * 8) * 64)
#define SGB(BT, I, KO) gload16(sB + (long)(I) * 49152 + (KO), (BT) + ((I) * 64 + uw * 8) * 64)
#define WBND asm volatile("s_waitcnt vmcnt(0)\n\ts_barrier" ::: "memory")
#define PBAR __builtin_amdgcn_s_barrier()

#define BODY(AC, BC, AN, BN, KOS, DOST)                                         \
  {                                                                             \
    short8 fa[4][2], fb0[2][2], fb1[2][2];                                      \
    if (DOST) { SGA(AN, 0, KOS); SGA(AN, 1, KOS); SGB(BN, 0, KOS); SGB(BN, 1, KOS); } \
    _Pragma("unroll")                                                           \
    for (int mi = 0; mi < 4; ++mi) {                                            \
      fa[mi][0] = *(const short8*)&AC[arb + mi * 1024 + ck0];                   \
      fa[mi][1] = *(const short8*)&AC[arb + mi * 1024 + ck1];                   \
    }                                                                           \
    _Pragma("unroll")                                                           \
    for (int ni = 0; ni < 2; ++ni) {                                            \
      fb0[ni][0] = *(const short8*)&BC[brb + ni * 1024 + ck0];                  \
      fb0[ni][1] = *(const short8*)&BC[brb + ni * 1024 + ck1];                  \
    }                                                                           \
    PBAR;                                                                       \
    __builtin_amdgcn_s_setprio(1);                                              \
    _Pragma("unroll")                                                           \
    for (int mi = 0; mi < 4; ++mi)                                              \
      _Pragma("unroll")                                                         \
      for (int ni = 0; ni < 2; ++ni) {                                          \
        acc[mi][ni] = __builtin_amdgcn_mfma_f32_16x16x32_bf16(fa[mi][0], fb0[ni][0], acc[mi][ni], 0, 0, 0); \
        acc[mi][ni] = __builtin_amdgcn_mfma_f32_16x16x32_bf16(fa[mi][1], fb0[ni][1], acc[mi][ni], 0, 0, 0); \
      }                                                                         \
    __builtin_amdgcn_s_setprio(0);                                              \
    PBAR;                                                                       \
    if (DOST) { SGA(AN, 2, KOS); SGA(AN, 3, KOS); SGB(BN, 2, KOS); SGB(BN, 3, KOS); } \
    _Pragma("unroll")                                                           \
    for (int ni = 0; ni < 2; ++ni) {                                            \
      fb1[ni][0] = *(const short8*)&BC[brb + (ni + 2) * 1024 + ck0];            \
      fb1[ni][1] = *(const short8*)&BC[brb + (ni + 2) * 1024 + ck1];            \
    }                                                                           \
    PBAR;                                                                       \
    __builtin_amdgcn_s_setprio(1);                                              \
    _Pragma("unroll")                                                           \
    for (int mi = 0; mi < 4; ++mi)                                              \
      _Pragma("unroll")                                                         \
      for (int ni = 0; ni < 2; ++ni) {                                          \
        acc[mi][ni + 2] = __builtin_amdgcn_mfma_f32_16x16x32_bf16(fa[mi][0], fb1[ni][0], acc[mi][ni + 2], 0, 0, 0); \
        acc[mi][ni + 2] = __builtin_amdgcn_mfma_f32_16x16x32_bf16(fa[mi][1], fb1[ni][1], acc[mi][ni + 2], 0, 0, 0); \
      }                                                                         \
    __builtin_amdgcn_s_setprio(0);                                              \
    PBAR;                                                                       \
    _Pragma("unroll")                                                           \
    for (int mi = 0; mi < 4; ++mi) {                                            \
      fa[mi][0] = *(const short8*)&AC[arb + (mi + 4) * 1024 + ck0];             \
      fa[mi][1] = *(const short8*)&AC[arb + (mi + 4) * 1024 + ck1];             \
    }                                                                           \
    PBAR;                                                                       \
    __builtin_amdgcn_s_setprio(1);                                              \
    _Pragma("unroll")                                                           \
    for (int mi = 0; mi < 4; ++mi)                                              \
      _Pragma("unroll")                                                         \
      for (int ni = 0; ni < 2; ++ni) {                                          \
        acc[mi + 4][ni + 2] = __builtin_amdgcn_mfma_f32_16x16x32_bf16(fa[mi][0], fb1[ni][0], acc[mi + 4][ni + 2], 0, 0, 0); \
        acc[mi + 4][ni + 2] = __builtin_amdgcn_mfma_f32_16x16x32_bf16(fa[mi][1], fb1[ni][1], acc[mi + 4][ni + 2], 0, 0, 0); \
      }                                                                         \
    __builtin_amdgcn_s_setprio(0);                                              \
    PBAR;                                                                       \
    __builtin_amdgcn_s_setprio(1);                                              \
    _Pragma("unroll")                                                           \
    for (int mi = 0; mi < 4; ++mi)                                              \
      _Pragma("unroll")                                                         \
      for (int ni = 0; ni < 2; ++ni) {                                          \
        acc[mi + 4][ni] = __builtin_amdgcn_mfma_f32_16x16x32_bf16(fa[mi][0], fb0[ni][0], acc[mi + 4][ni], 0, 0, 0); \
        acc[mi + 4][ni] = __builtin_amdgcn_mfma_f32_16x16x32_bf16(fa[mi][1], fb0[ni][1], acc[mi + 4][ni], 0, 0, 0); \
      }                                                                         \
    __builtin_amdgcn_s_setprio(0);                                              \
  }

#define GEMM_PROLOGUE                                                           \
  int bid = blockIdx.x;                                                         \
  int lb = (bid & 7) * 768 + (bid >> 3);                                        \
  int mt = lb / 6;                                                              \
  int nt = lb - mt * 6;                                                         \
  long m0 = (long)mt * 256;                                                     \
  int n0 = nt * 256;                                                            \
  int tid = threadIdx.x;                                                        \
  int lane = tid & 63;                                                          \
  int uw = __builtin_amdgcn_readfirstlane(tid >> 6);                            \
  int wm = uw >> 2;                                                             \
  int wn = uw & 3;                                                              \
  int r16 = lane & 15;                                                          \
  int gk = lane >> 4;                                                           \
  const unsigned short* xs = xb + m0 * 768;                                     \
  const unsigned short* wp = Wt + (long)n0 * 768;                               \
  int srow8 = lane >> 3;                                                        \
  int sch = ((lane & 7) ^ (srow8 & 7)) << 3;                                    \
  const unsigned short* sA = xs + (long)(uw * 8 + srow8) * 768 + sch;           \
  const unsigned short* sB = wp + (long)(uw * 8 + srow8) * 768 + sch;           \
  int ck0 = ((gk ^ (r16 & 7)) << 3);                                            \
  int ck1 = (((4 + gk) ^ (r16 & 7)) << 3);                                      \
  int arb = (wm * 128 + r16) * 64;                                              \
  int brb = (wn * 64 + r16) * 64;                                               \
  f32x4 acc[8][4];                                                              \
  _Pragma("unroll")                                                             \
  for (int i = 0; i < 8; ++i)                                                   \
    _Pragma("unroll")                                                           \
    for (int j = 0; j < 4; ++j) acc[i][j] = (f32x4){0.f, 0.f, 0.f, 0.f};        \
  SGA(A0T, 0, 0); SGA(A0T, 1, 0); SGA(A0T, 2, 0); SGA(A0T, 3, 0);               \
  SGB(B0T, 0, 0); SGB(B0T, 1, 0); SGB(B0T, 2, 0); SGB(B0T, 3, 0);               \
  WBND;                                                                         \
  _Pragma("unroll 1")                                                           \
  for (int t = 0; t < 12; t += 2) {                                             \
    BODY(A0T, B0T, A1T, B1T, (t + 1) * 64, true);                               \
    WBND;                                                                       \
    BODY(A1T, B1T, A0T, B0T, (t + 2) * 64, (t + 2) < 12);                       \
    WBND;                                                                       \
  }

// ---------------------------------------------------------------------------
// Kernel 3 (R10 proven, 734 us): 256x256 BK=64 4-phase gemm, k bf16 + v fp32.
// ---------------------------------------------------------------------------
__global__ __launch_bounds__(512, 2) void gemm_kv8(const unsigned short* __restrict__ xb,
                                                   const unsigned short* __restrict__ Wt,
                                                   unsigned short* __restrict__ k_ws,
                                                   float* __restrict__ v_out) {
  __shared__ char smem[131072];
  unsigned short* A0T = (unsigned short*)(smem);
  unsigned short* B0T = (unsigned short*)(smem + 32768);
  unsigned short* A1T = (unsigned short*)(smem + 65536);
  unsigned short* B1T = (unsigned short*)(smem + 98304);
  GEMM_PROLOGUE

  float* scr = (float*)smem + uw * 1088;
  bool is_k = (n0 < 768);
  int h = (is_k ? (n0 >> 6) : ((n0 - 768) >> 6)) + wn;
  int bq = (int)(m0 >> 12);
  int nb = (int)(m0 & 4095) + wm * 128;
#pragma unroll
  for (int mi = 0; mi < 8; ++mi) {
#pragma unroll
    for (int ni = 0; ni < 4; ++ni)
#pragma unroll
      for (int r = 0; r < 4; ++r)
        scr[(gk * 4 + r) * 68 + ni * 16 + r16] = acc[mi][ni][r];
    int nbase = nb + mi * 16;
    if (is_k) {
#pragma unroll
      for (int p = 0; p < 2; ++p) {
        int row = p * 8 + (lane >> 3);
        int d0 = (lane & 7) << 3;
        float4 aa = *(const float4*)&scr[row * 68 + d0];
        float4 bb = *(const float4*)&scr[row * 68 + d0 + 4];
        short8 hh;
        hh[0] = (short)f2bf(aa.x); hh[1] = (short)f2bf(aa.y);
        hh[2] = (short)f2bf(aa.z); hh[3] = (short)f2bf(aa.w);
        hh[4] = (short)f2bf(bb.x); hh[5] = (short)f2bf(bb.y);
        hh[6] = (short)f2bf(bb.z); hh[7] = (short)f2bf(bb.w);
        *(short8*)&k_ws[((long)(bq * 12 + h) * 4096 + nbase + row) * 64 + d0] = hh;
      }
    } else {
#pragma unroll
      for (int p = 0; p < 4; ++p) {
        int row = p * 4 + (lane >> 4);
        int d0 = (lane & 15) << 2;
        float4 aa = *(const float4*)&scr[row * 68 + d0];
        *(float4*)&v_out[((long)(bq * 12 + h) * 4096 + nbase + row) * 64 + d0] = aa;
      }
    }
  }
}

#undef GEMM_PROLOGUE
#undef BODY
#undef SGA
#undef SGB
#undef WBND
#undef PBAR

// ---------------------------------------------------------------------------
// Kernel 3-FALLBACK (R1 version, used when ws_size is too small)
// ---------------------------------------------------------------------------
__global__ __launch_bounds__(256) void gemm_kv(const float* __restrict__ x,
                                               const unsigned short* __restrict__ Wt,
                                               unsigned short* __restrict__ k_ws,
                                               float* __restrict__ v_out) {
  __shared__ char lds[32768];
  int bid = blockIdx.x;
  int lb = (bid & 7) * 3072 + (bid >> 3);
  int mt = lb / 12, nt = lb - mt * 12;
  long m0 = (long)mt * 128; int n0 = nt * 128;
  int tid = threadIdx.x, lane = tid & 63;
  int wid = tid >> 6, wm = wid >> 1, wn = wid & 1;
  int rlo = lane & 15, gk = lane >> 4;

  const float* xs = x + m0 * 768;
  const unsigned short* wp = Wt + (long)n0 * 768;

  int arow0 = tid >> 3, ak4 = (tid & 7) << 2;
  int bn = tid >> 1, bg = (tid & 1) << 1;

  f32x4 acc[4][4];
#pragma unroll
  for (int i = 0; i < 4; ++i)
#pragma unroll
    for (int j = 0; j < 4; ++j) acc[i][j] = (f32x4){0.f, 0.f, 0.f, 0.f};

  float4 fA[4]; short8 wB[2];
#pragma unroll
  for (int it = 0; it < 4; ++it) {
    int row = it * 32 + arow0;
    fA[it] = *(const float4*)(xs + (long)row * 768 + ak4);
  }
#pragma unroll
  for (int i = 0; i < 2; ++i)
    wB[i] = *(const short8*)(wp + (long)bn * 768 + (bg + i) * 8);
#pragma unroll
  for (int it = 0; it < 4; ++it) {
    int row = it * 32 + arow0;
    short4v h;
    h[0] = (short)f2bf(fA[it].x); h[1] = (short)f2bf(fA[it].y);
    h[2] = (short)f2bf(fA[it].z); h[3] = (short)f2bf(fA[it].w);
    *(short4v*)(lds + row * 64 + ((ak4 * 2) ^ (((row >> 1) & 3) << 4))) = h;
  }
#pragma unroll
  for (int i = 0; i < 2; ++i)
    *(short8*)(lds + 16384 + bn * 64 + (((bg + i) * 16) ^ (((bn >> 1) & 3) << 4))) = wB[i];
  __syncthreads();

#pragma unroll 2
  for (int ks = 0; ks < 24; ++ks) {
    char* Ab = lds + (ks & 1) * 8192;
    char* Bb = lds + 16384 + (ks & 1) * 8192;
    bool pf = (ks + 1 < 24);
    if (pf) {
#pragma unroll
      for (int it = 0; it < 4; ++it) {
        int row = it * 32 + arow0;
        fA[it] = *(const float4*)(xs + (long)row * 768 + (ks + 1) * 32 + ak4);
      }
#pragma unroll
      for (int i = 0; i < 2; ++i)
        wB[i] = *(const short8*)(wp + (long)bn * 768 + (ks + 1) * 32 + (bg + i) * 8);
    }
    short8 af[4], bfr[4];
#pragma unroll
    for (int mi = 0; mi < 4; ++mi) {
      int row = wm * 64 + mi * 16 + rlo;
      af[mi] = *(const short8*)(Ab + row * 64 + ((gk * 16) ^ (((row >> 1) & 3) << 4)));
    }
#pragma unroll
    for (int ni = 0; ni < 4; ++ni) {
      int n = wn * 64 + ni * 16 + rlo;
      bfr[ni] = *(const short8*)(Bb + n * 64 + ((gk * 16) ^ (((n >> 1) & 3) << 4)));
    }
#pragma unroll
    for (int mi = 0; mi < 4; ++mi)
#pragma unroll
      for (int ni = 0; ni < 4; ++ni)
        acc[mi][ni] = __builtin_amdgcn_mfma_f32_16x16x32_bf16(af[mi], bfr[ni], acc[mi][ni], 0, 0, 0);
    if (pf) {
      char* An = lds + ((ks + 1) & 1) * 8192;
      char* Bn = lds + 16384 + ((ks + 1) & 1) * 8192;
#pragma unroll
      for (int it = 0; it < 4; ++it) {
        int row = it * 32 + arow0;
        short4v h;
        h[0] = (short)f2bf(fA[it].x); h[1] = (short)f2bf(fA[it].y);
        h[2] = (short)f2bf(fA[it].z); h[3] = (short)f2bf(fA[it].w);
        *(short4v*)(An + row * 64 + ((ak4 * 2) ^ (((row >> 1) & 3) << 4))) = h;
      }
#pragma unroll
      for (int i = 0; i < 2; ++i)
        *(short8*)(Bn + bn * 64 + (((bg + i) * 16) ^ (((bn >> 1) & 3) << 4))) = wB[i];
    }
    __syncthreads();
  }

  bool is_k = (n0 < 768);
  int cb = is_k ? n0 : n0 - 768;
#pragma unroll
  for (int ni = 0; ni < 4; ++ni) {
    int cc = cb + wn * 64 + ni * 16 + rlo;
    int h = cc >> 6, d = cc & 63;
#pragma unroll
    for (int mi = 0; mi < 4; ++mi) {
#pragma unroll
      for (int r = 0; r < 4; ++r) {
        long m = m0 + wm * 64 + mi * 16 + gk * 4 + r;
        int b = (int)(m >> 12), n = (int)(m & 4095);
        long off = ((long)(b * 12 + h) * 4096 + n) * 64 + d;
        float val = acc[mi][ni][r];
        if (is_k) k_ws[off] = f2bf(val);
        else      v_out[off] = val;
      }
    }
  }
}

// ---------------------------------------------------------------------------
// Kernel 4 (R18): 16-wave attn — 1024 threads, wave owns 256 cols. 2x TLP
// on the latency-bound v-gathers. Single-exp fused P3 (R15 numerics).
// blob = pbuf 80K + part 64K + red 4.5K = 148.6 KB (<160 KB LDS/CU).
// ---------------------------------------------------------------------------
__global__ __launch_bounds__(1024) void attn_fused7(const unsigned short* __restrict__ k_ws,
                                                    const unsigned short* __restrict__ q_ws,
                                                    const float* __restrict__ v_glob,
                                                    float* __restrict__ attn_out,
                                                    float* __restrict__ preproj) {
  __shared__ char blob[148608];
  unsigned short* pbuf = (unsigned short*)blob;       // [16 waves][10 rows][256] bf16, swizzled
  float* part = (float*)(blob + 81920);               // [16 waves][1024] fp32
  float* redm = (float*)(blob + 147456);              // [16][16]
  float* rowmax16 = (float*)(blob + 148480);          // [16]
  float* rowinv16 = rowmax16 + 16;                    // [16]

  int tid = threadIdx.x, lane = tid & 63, w = tid >> 6;   // w = 0..15
  int bh = blockIdx.x;
  int r16 = lane & 15, gk = lane >> 4;
  int trc = (r16 < 10) ? r16 : 9;
  int nW = w << 8;                                    // 256 cols per wave

  const unsigned short* kp = k_ws + (long)bh * (4096 * 64);
  const unsigned short* qp = q_ws + (long)bh * 1024;
  float* sraw = attn_out + (long)bh * 40960;
  const float* vp = v_glob + (long)bh * (4096 * 64);

  short8 qf0 = *(const short8*)(qp + r16 * 64 + gk * 8);
  short8 qf1 = *(const short8*)(qp + r16 * 64 + 32 + gk * 8);

  char* pbw = (char*)pbuf + w * 5120 + r16 * 512;     // own-row write base (512B rows)
  int swz = (r16 & 7) << 4;

  // ---- P1: QK -> masked bf16 scores to pbuf + row max (16 chunks/wave) ----
  float pmax = -3.0e38f;
#pragma unroll 4
  for (int ch = 0; ch < 16; ++ch) {
    int n0 = nW + (ch << 4);
    short8 kf0 = *(const short8*)(kp + (long)(n0 + r16) * 64 + gk * 8);
    short8 kf1 = *(const short8*)(kp + (long)(n0 + r16) * 64 + 32 + gk * 8);
    f32x4 d4 = (f32x4){0.f, 0.f, 0.f, 0.f};
    d4 = __builtin_amdgcn_mfma_f32_16x16x32_bf16(kf0, qf0, d4, 0, 0, 0);
    d4 = __builtin_amdgcn_mfma_f32_16x16x32_bf16(kf1, qf1, d4, 0, 0, 0);
#pragma unroll
    for (int r = 0; r < 4; ++r) {
      int n = n0 + gk * 4 + r;
      float v = d4[r];
      if (n < 10 && n != r16) v = -1e30f;
      d4[r] = v;
      pmax = fmaxf(pmax, v);
    }
    if (r16 < 10) {
      short4v h4;
      h4[0] = (short)f2bf(d4[0]); h4[1] = (short)f2bf(d4[1]);
      h4[2] = (short)f2bf(d4[2]); h4[3] = (short)f2bf(d4[3]);
      *(short4v*)(pbw + ((ch * 32 + gk * 8) ^ swz)) = h4;
    }
  }
  pmax = fmaxf(pmax, __shfl_xor(pmax, 16));
  pmax = fmaxf(pmax, __shfl_xor(pmax, 32));
  if (lane < 16) redm[w * 16 + lane] = pmax;
  __syncthreads();
  if (tid < 16) {
    float m = redm[tid];
#pragma unroll
    for (int i = 1; i < 16; ++i) m = fmaxf(m, redm[i * 16 + tid]);
    rowmax16[tid] = m;
  }
  __syncthreads();

  // ---- P2: read-back own row (512B = 8 x 64B), exp + sum ----
  float mx = rowmax16[trc];
  char* pbr = (char*)pbuf + w * 5120 + trc * 512;
  int swr = (trc & 7) << 4;
  float psum = 0.f;
#pragma unroll 4
  for (int i = 0; i < 8; ++i) {
    short8 sv = *(const short8*)(pbr + ((i * 64 + gk * 16) ^ swr));
#pragma unroll
    for (int j = 0; j < 8; ++j) psum += __expf(bf2f((unsigned short)sv[j]) - mx);
  }
  psum += __shfl_xor(psum, 16);
  psum += __shfl_xor(psum, 32);
  if (lane < 16) redm[w * 16 + lane] = psum;
  __syncthreads();
  if (tid < 16) {
    float t = 0.f;
#pragma unroll
    for (int i = 0; i < 16; ++i) t += redm[i * 16 + tid];
    rowinv16[tid] = 1.0f / t;
  }
  __syncthreads();
  float inv = rowinv16[trc];

  // ---- P3 (fused): p computed once -> fp32 attn write + PV A-frag ----
  f32x4 pacc[4];
#pragma unroll
  for (int dc = 0; dc < 4; ++dc) pacc[dc] = (f32x4){0.f, 0.f, 0.f, 0.f};
#pragma unroll 4
  for (int ks = 0; ks < 8; ++ks) {
    short8 raw = *(const short8*)(pbr + ((ks * 64 + gk * 16) ^ swr));
    float p0 = __expf(bf2f((unsigned short)raw[0]) - mx) * inv;
    float p1 = __expf(bf2f((unsigned short)raw[1]) - mx) * inv;
    float p2 = __expf(bf2f((unsigned short)raw[2]) - mx) * inv;
    float p3 = __expf(bf2f((unsigned short)raw[3]) - mx) * inv;
    float p4 = __expf(bf2f((unsigned short)raw[4]) - mx) * inv;
    float p5 = __expf(bf2f((unsigned short)raw[5]) - mx) * inv;
    float p6 = __expf(bf2f((unsigned short)raw[6]) - mx) * inv;
    float p7 = __expf(bf2f((unsigned short)raw[7]) - mx) * inv;
    if (r16 < 10) {                                   // pbr==pbw here: same values
      float* gp = sraw + r16 * 4096 + nW + ks * 32 + gk * 8;
      *(float4*)gp = make_float4(p0, p1, p2, p3);
      *(float4*)(gp + 4) = make_float4(p4, p5, p6, p7);
    }
    short8 pa;
    pa[0] = (short)f2bf(p0); pa[1] = (short)f2bf(p1);
    pa[2] = (short)f2bf(p2); pa[3] = (short)f2bf(p3);
    pa[4] = (short)f2bf(p4); pa[5] = (short)f2bf(p5);
    pa[6] = (short)f2bf(p6); pa[7] = (short)f2bf(p7);
    const float* vbase = vp + (long)(nW + ks * 32 + gk * 8) * 64 + r16;
#pragma unroll
    for (int dc = 0; dc < 4; ++dc) {
      short8 vb;
      const float* vrow = vbase + dc * 16;
#pragma unroll
      for (int j = 0; j < 8; ++j) vb[j] = (short)f2bf(vrow[j * 64]);
      pacc[dc] = __builtin_amdgcn_mfma_f32_16x16x32_bf16(pa, vb, pacc[dc], 0, 0, 0);
    }
  }
#pragma unroll
  for (int dc = 0; dc < 4; ++dc)
#pragma unroll
    for (int r = 0; r < 4; ++r)
      part[w * 1024 + dc * 256 + (gk * 4 + r) * 16 + r16] = pacc[dc][r];
  __syncthreads();

  // ---- P4: 16-way cross-wave reduce + preproj write ----
  int b = bh / 12, h = bh - b * 12;
  for (int idx = tid; idx < 640; idx += 1024) {
    int tt = idx >> 6, d = idx & 63;
    int dc = d >> 4, dl = d & 15;
    float sum = 0.f;
#pragma unroll
    for (int i = 0; i < 16; ++i) sum += part[i * 1024 + dc * 256 + tt * 16 + dl];
    preproj[((long)b * 10 + tt) * 768 + h * 64 + d] = sum;
  }
}

// ---------------------------------------------------------------------------
// Kernel 5: x_cls = preproj @ Wp + bp
// ---------------------------------------------------------------------------
__global__ __launch_bounds__(256) void proj_out_k(const float* __restrict__ preproj,
                                                  const float* __restrict__ Wp,
                                                  const float* __restrict__ bp,
                                                  float* __restrict__ out0) {
  int b = blockIdx.x, tid = threadIdx.x;
  __shared__ float xr[7680];
  const float* pp = preproj + (long)b * 7680;
  for (int i = tid; i < 7680; i += 256) xr[i] = pp[i];
  __syncthreads();
  float acc[10][3];
#pragma unroll
  for (int t = 0; t < 10; ++t) { acc[t][0] = 0.f; acc[t][1] = 0.f; acc[t][2] = 0.f; }
  for (int k = 0; k < 768; ++k) {
    const float* wr = Wp + (long)k * 768;
    float w0 = wr[tid], w1 = wr[tid + 256], w2 = wr[tid + 512];
#pragma unroll
    for (int t = 0; t < 10; ++t) {
      float xv = xr[t * 768 + k];
      acc[t][0] += xv * w0; acc[t][1] += xv * w1; acc[t][2] += xv * w2;
    }
  }
  float b0 = bp[tid], b1 = bp[tid + 256], b2 = bp[tid + 512];
  float* op = out0 + (long)b * 7680;
#pragma unroll
  for (int t = 0; t < 10; ++t) {
    op[t * 768 + tid]       = acc[t][0] + b0;
    op[t * 768 + tid + 256] = acc[t][1] + b1;
    op[t * 768 + tid + 512] = acc[t][2] + b2;
  }
}

// ---------------------------------------------------------------------------
extern "C" void kernel_launch(void* const* d_in, const int* in_sizes, int n_in,
                              void* d_out, int out_size, void* d_ws, size_t ws_size,
                              hipStream_t stream) {
  (void)in_sizes; (void)n_in; (void)out_size;
  const float* x  = (const float*)d_in[0];
  const float* Wq = (const float*)d_in[1];
  const float* Wk = (const float*)d_in[2];
  const float* Wv = (const float*)d_in[3];
  const float* Wp = (const float*)d_in[4];
  const float* bp = (const float*)d_in[5];

  float* out      = (float*)d_out;
  float* attn_out = out + 491520;                 // [64,12,10,4096]
  float* v_out    = out + 31948800;               // [64,12,4096,64]

  char* ws = (char*)d_ws;
  const size_t NEED_BIG = 811204608;              // x_bf16 + k_ws + small (proven)

  if (ws_size >= NEED_BIG) {
    unsigned short* x_bf16 = (unsigned short*)(ws);                 // 402,653,184 B
    unsigned short* k_ws   = (unsigned short*)(ws + 402653184);     // 402,653,184 B
    unsigned short* q_ws   = (unsigned short*)(ws + 805306368);     //   1,572,864 B
    unsigned short* Wt     = (unsigned short*)(ws + 806879232);     //   2,359,296 B
    float* preproj         = (float*)(ws + 809238528);              //   1,966,080 B

    conv_x<<<dim3(2048), dim3(256), 0, stream>>>(x, x_bf16);
    prep_w<<<dim3(4608), dim3(256), 0, stream>>>(Wk, Wv, Wt);
    q_proj<<<dim3(64), dim3(256), 0, stream>>>(x, Wq, q_ws);
    gemm_kv8<<<dim3(6144), dim3(512), 0, stream>>>(x_bf16, Wt, k_ws, v_out);
    attn_fused7<<<dim3(768), dim3(1024), 0, stream>>>(k_ws, q_ws, v_out, attn_out, preproj);
    proj_out_k<<<dim3(64), dim3(256), 0, stream>>>(preproj, Wp, bp, out);
  } else {
    unsigned short* k_ws = (unsigned short*)(ws);                   // 402,653,184 B
    unsigned short* q_ws = (unsigned short*)(ws + 402653184);
    unsigned short* Wt   = (unsigned short*)(ws + 404226048);
    float* preproj       = (float*)(ws + 406585344);

    prep_w<<<dim3(4608), dim3(256), 0, stream>>>(Wk, Wv, Wt);
    q_proj<<<dim3(64), dim3(256), 0, stream>>>(x, Wq, q_ws);
    gemm_kv<<<dim3(24576), dim3(256), 0, stream>>>(x, Wt, k_ws, v_out);
    attn_fused7<<<dim3(768), dim3(1024), 0, stream>>>(k_ws, q_ws, v_out, attn_out, preproj);
    proj_out_k<<<dim3(64), dim3(256), 0, stream>>>(preproj, Wp, bp, out);
  }
}

// Round 19
// 1482.393 us; speedup vs baseline: 1.0076x; 1.0076x over previous
//
#include <hip/hip_runtime.h>

typedef __attribute__((ext_vector_type(8))) short short8;
typedef __attribute__((ext_vector_type(4))) short short4v;
typedef __attribute__((ext_vector_type(4))) float f32x4;

__device__ __forceinline__ unsigned short f2bf(float f) {
  union { float f; unsigned u; } v; v.f = f;
  unsigned r = v.u + 0x7FFFu + ((v.u >> 16) & 1u);
  return (unsigned short)(r >> 16);
}

__device__ __forceinline__ float bf2f(unsigned short h) {
  union { unsigned u; float f; } v; v.u = ((unsigned)h) << 16;
  return v.f;
}

__device__ __forceinline__ void gload16(const void* g, void* l) {
  __builtin_amdgcn_global_load_lds(
      (const __attribute__((address_space(1))) void*)g,
      (__attribute__((address_space(3))) void*)l, 16, 0, 0);
}

// ---------------------------------------------------------------------------
// Kernel 0: x (fp32) -> x_bf16, vectorized 8 elems/thread
// ---------------------------------------------------------------------------
__global__ __launch_bounds__(256) void conv_x(const float* __restrict__ x,
                                              unsigned short* __restrict__ xb) {
  const long total = 25165824;                        // 201326592 / 8
  long stride = (long)gridDim.x * 256;
  for (long u = blockIdx.x * 256 + threadIdx.x; u < total; u += stride) {
    const float* p = x + u * 8;
    float4 a = *(const float4*)p;
    float4 b = *(const float4*)(p + 4);
    short8 h;
    h[0] = (short)f2bf(a.x); h[1] = (short)f2bf(a.y);
    h[2] = (short)f2bf(a.z); h[3] = (short)f2bf(a.w);
    h[4] = (short)f2bf(b.x); h[5] = (short)f2bf(b.y);
    h[6] = (short)f2bf(b.z); h[7] = (short)f2bf(b.w);
    *(short8*)(xb + u * 8) = h;
  }
}

// ---------------------------------------------------------------------------
// Kernel 1: Wt[n][k] = bf16( [Wk | Wv](k, n) )   (B^T layout, n in [0,1536))
// ---------------------------------------------------------------------------
__global__ __launch_bounds__(256) void prep_w(const float* __restrict__ Wk,
                                              const float* __restrict__ Wv,
                                              unsigned short* __restrict__ Wt) {
  int idx = blockIdx.x * 256 + threadIdx.x;           // 1536*768 elements
  int n = idx / 768, k = idx - n * 768;
  float w = (n < 768) ? Wk[k * 768 + n] : Wv[k * 768 + (n - 768)];
  Wt[idx] = f2bf(w);
}

// ---------------------------------------------------------------------------
// Kernel 2: q = scale * x[:, :10] @ Wq  -> q_ws[b][h][16][64] bf16 (rows 10..15 = 0)
// ---------------------------------------------------------------------------
__global__ __launch_bounds__(256) void q_proj(const float* __restrict__ x,
                                              const float* __restrict__ Wq,
                                              unsigned short* __restrict__ q_ws) {
  int b = blockIdx.x, tid = threadIdx.x;
  __shared__ float xr[7680];
  const float* xp = x + (long)b * 4096 * 768;
  for (int i = tid; i < 7680; i += 256) xr[i] = xp[i];
  for (int i = tid; i < 12 * 6 * 64; i += 256) {
    int h = i / 384, rem = i - h * 384;
    int t = 10 + rem / 64, d = rem & 63;
    q_ws[(((long)(b * 12 + h) * 16 + t) << 6) + d] = 0;
  }
  __syncthreads();
  float acc[10][3];
#pragma unroll
  for (int t = 0; t < 10; ++t) { acc[t][0] = 0.f; acc[t][1] = 0.f; acc[t][2] = 0.f; }
  for (int k = 0; k < 768; ++k) {
    const float* wr = Wq + (long)k * 768;
    float w0 = wr[tid], w1 = wr[tid + 256], w2 = wr[tid + 512];
#pragma unroll
    for (int t = 0; t < 10; ++t) {
      float xv = xr[t * 768 + k];
      acc[t][0] += xv * w0; acc[t][1] += xv * w1; acc[t][2] += xv * w2;
    }
  }
#pragma unroll
  for (int t = 0; t < 10; ++t) {
#pragma unroll
    for (int j = 0; j < 3; ++j) {
      int c = tid + j * 256;
      int h = c >> 6, d = c & 63;
      q_ws[(((long)(b * 12 + h) * 16 + t) << 6) + d] = f2bf(acc[t][j] * 0.125f);
    }
  }
}

// ---------------------------------------------------------------------------
// Shared macros for the 256x256 BK=64 4-phase GEMM core (R8/R10 proven)
// ---------------------------------------------------------------------------
#define SGA(AT, I, KO) gload16(sA + (long)(I) * 49152 + (KO), (AT) + ((I) * 64 + uw * 8) * 64)
#define SGB(BT, I, KO) gload16(sB + (long)(I) * 49152 + (KO), (BT) + ((I) * 64 + uw * 8) * 64)
#define WBND asm volatile("s_waitcnt vmcnt(0)\n\ts_barrier" ::: "memory")
#define PBAR __builtin_amdgcn_s_barrier()

#define BODY(AC, BC, AN, BN, KOS, DOST)                                         \
  {                                                                             \
    short8 fa[4][2], fb0[2][2], fb1[2][2];                                      \
    if (DOST) { SGA(AN, 0, KOS); SGA(AN, 1, KOS); SGB(BN, 0, KOS); SGB(BN, 1, KOS); } \
    _Pragma("unroll")                                                           \
    for (int mi = 0; mi < 4; ++mi) {                                            \
      fa[mi][0] = *(const short8*)&AC[arb + mi * 1024 + ck0];                   \
      fa[mi][1] = *(const short8*)&AC[arb + mi * 1024 + ck1];                   \
    }                                                                           \
    _Pragma("unroll")                                                           \
    for (int ni = 0; ni < 2; ++ni) {                                            \
      fb0[ni][0] = *(const short8*)&BC[brb + ni * 1024 + ck0];                  \
      fb0[ni][1] = *(const short8*)&BC[brb + ni * 1024 + ck1];                  \
    }                                                                           \
    PBAR;                                                                       \
    __builtin_amdgcn_s_setprio(1);                                              \
    _Pragma("unroll")                                                           \
    for (int mi = 0; mi < 4; ++mi)                                              \
      _Pragma("unroll")                                                         \
      for (int ni = 0; ni < 2; ++ni) {                                          \
        acc[mi][ni] = __builtin_amdgcn_mfma_f32_16x16x32_bf16(fa[mi][0], fb0[ni][0], acc[mi][ni], 0, 0, 0); \
        acc[mi][ni] = __builtin_amdgcn_mfma_f32_16x16x32_bf16(fa[mi][1], fb0[ni][1], acc[mi][ni], 0, 0, 0); \
      }                                                                         \
    __builtin_amdgcn_s_setprio(0);                                              \
    PBAR;                                                                       \
    if (DOST) { SGA(AN, 2, KOS); SGA(AN, 3, KOS); SGB(BN, 2, KOS); SGB(BN, 3, KOS); } \
    _Pragma("unroll")                                                           \
    for (int ni = 0; ni < 2; ++ni) {                                            \
      fb1[ni][0] = *(const short8*)&BC[brb + (ni + 2) * 1024 + ck0];            \
      fb1[ni][1] = *(const short8*)&BC[brb + (ni + 2) * 1024 + ck1];            \
    }                                                                           \
    PBAR;                                                                       \
    __builtin_amdgcn_s_setprio(1);                                              \
    _Pragma("unroll")                                                           \
    for (int mi = 0; mi < 4; ++mi)                                              \
      _Pragma("unroll")                                                         \
      for (int ni = 0; ni < 2; ++ni) {                                          \
        acc[mi][ni + 2] = __builtin_amdgcn_mfma_f32_16x16x32_bf16(fa[mi][0], fb1[ni][0], acc[mi][ni + 2], 0, 0, 0); \
        acc[mi][ni + 2] = __builtin_amdgcn_mfma_f32_16x16x32_bf16(fa[mi][1], fb1[ni][1], acc[mi][ni + 2], 0, 0, 0); \
      }                                                                         \
    __builtin_amdgcn_s_setprio(0);                                              \
    PBAR;                                                                       \
    _Pragma("unroll")                                                           \
    for (int mi = 0; mi < 4; ++mi) {                                            \
      fa[mi][0] = *(const short8*)&AC[arb + (mi + 4) * 1024 + ck0];             \
      fa[mi][1] = *(const short8*)&AC[arb + (mi + 4) * 1024 + ck1];             \
    }                                                                           \
    PBAR;                                                                       \
    __builtin_amdgcn_s_setprio(1);                                              \
    _Pragma("unroll")                                                           \
    for (int mi = 0; mi < 4; ++mi)                                              \
      _Pragma("unroll")                                                         \
      for (int ni = 0; ni < 2; ++ni) {                                          \
        acc[mi + 4][ni + 2] = __builtin_amdgcn_mfma_f32_16x16x32_bf16(fa[mi][0], fb1[ni][0], acc[mi + 4][ni + 2], 0, 0, 0); \
        acc[mi + 4][ni + 2] = __builtin_amdgcn_mfma_f32_16x16x32_bf16(fa[mi][1], fb1[ni][1], acc[mi + 4][ni + 2], 0, 0, 0); \
      }                                                                         \
    __builtin_amdgcn_s_setprio(0);                                              \
    PBAR;                                                                       \
    __builtin_amdgcn_s_setprio(1);                                              \
    _Pragma("unroll")                                                           \
    for (int mi = 0; mi < 4; ++mi)                                              \
      _Pragma("unroll")                                                         \
      for (int ni = 0; ni < 2; ++ni) {                                          \
        acc[mi + 4][ni] = __builtin_amdgcn_mfma_f32_16x16x32_bf16(fa[mi][0], fb0[ni][0], acc[mi + 4][ni], 0, 0, 0); \
        acc[mi + 4][ni] = __builtin_amdgcn_mfma_f32_16x16x32_bf16(fa[mi][1], fb0[ni][1], acc[mi + 4][ni], 0, 0, 0); \
      }                                                                         \
    __builtin_amdgcn_s_setprio(0);                                              \
  }

#define GEMM_PROLOGUE                                                           \
  int bid = blockIdx.x;                                                         \
  int lb = (bid & 7) * 768 + (bid >> 3);                                        \
  int mt = lb / 6;                                                              \
  int nt = lb - mt * 6;                                                         \
  long m0 = (long)mt * 256;                                                     \
  int n0 = nt * 256;                                                            \
  int tid = threadIdx.x;                                                        \
  int lane = tid & 63;                                                          \
  int uw = __builtin_amdgcn_readfirstlane(tid >> 6);                            \
  int wm = uw >> 2;                                                             \
  int wn = uw & 3;                                                              \
  int r16 = lane & 15;                                                          \
  int gk = lane >> 4;                                                           \
  const unsigned short* xs = xb + m0 * 768;                                     \
  const unsigned short* wp = Wt + (long)n0 * 768;                               \
  int srow8 = lane >> 3;                                                        \
  int sch = ((lane & 7) ^ (srow8 & 7)) << 3;                                    \
  const unsigned short* sA = xs + (long)(uw * 8 + srow8) * 768 + sch;           \
  const unsigned short* sB = wp + (long)(uw * 8 + srow8) * 768 + sch;           \
  int ck0 = ((gk ^ (r16 & 7)) << 3);                                            \
  int ck1 = (((4 + gk) ^ (r16 & 7)) << 3);                                      \
  int arb = (wm * 128 + r16) * 64;                                              \
  int brb = (wn * 64 + r16) * 64;                                               \
  f32x4 acc[8][4];                                                              \
  _Pragma("unroll")                                                             \
  for (int i = 0; i < 8; ++i)                                                   \
    _Pragma("unroll")                                                           \
    for (int j = 0; j < 4; ++j) acc[i][j] = (f32x4){0.f, 0.f, 0.f, 0.f};        \
  SGA(A0T, 0, 0); SGA(A0T, 1, 0); SGA(A0T, 2, 0); SGA(A0T, 3, 0);               \
  SGB(B0T, 0, 0); SGB(B0T, 1, 0); SGB(B0T, 2, 0); SGB(B0T, 3, 0);               \
  WBND;                                                                         \
  _Pragma("unroll 1")                                                           \
  for (int t = 0; t < 12; t += 2) {                                             \
    BODY(A0T, B0T, A1T, B1T, (t + 1) * 64, true);                               \
    WBND;                                                                       \
    BODY(A1T, B1T, A0T, B0T, (t + 2) * 64, (t + 2) < 12);                       \
    WBND;                                                                       \
  }

// ---------------------------------------------------------------------------
// Kernel 3 (R10 proven, 734 us): 256x256 BK=64 4-phase gemm, k bf16 + v fp32.
// ---------------------------------------------------------------------------
__global__ __launch_bounds__(512, 2) void gemm_kv8(const unsigned short* __restrict__ xb,
                                                   const unsigned short* __restrict__ Wt,
                                                   unsigned short* __restrict__ k_ws,
                                                   float* __restrict__ v_out) {
  __shared__ char smem[131072];
  unsigned short* A0T = (unsigned short*)(smem);
  unsigned short* B0T = (unsigned short*)(smem + 32768);
  unsigned short* A1T = (unsigned short*)(smem + 65536);
  unsigned short* B1T = (unsigned short*)(smem + 98304);
  GEMM_PROLOGUE

  float* scr = (float*)smem + uw * 1088;
  bool is_k = (n0 < 768);
  int h = (is_k ? (n0 >> 6) : ((n0 - 768) >> 6)) + wn;
  int bq = (int)(m0 >> 12);
  int nb = (int)(m0 & 4095) + wm * 128;
#pragma unroll
  for (int mi = 0; mi < 8; ++mi) {
#pragma unroll
    for (int ni = 0; ni < 4; ++ni)
#pragma unroll
      for (int r = 0; r < 4; ++r)
        scr[(gk * 4 + r) * 68 + ni * 16 + r16] = acc[mi][ni][r];
    int nbase = nb + mi * 16;
    if (is_k) {
#pragma unroll
      for (int p = 0; p < 2; ++p) {
        int row = p * 8 + (lane >> 3);
        int d0 = (lane & 7) << 3;
        float4 aa = *(const float4*)&scr[row * 68 + d0];
        float4 bb = *(const float4*)&scr[row * 68 + d0 + 4];
        short8 hh;
        hh[0] = (short)f2bf(aa.x); hh[1] = (short)f2bf(aa.y);
        hh[2] = (short)f2bf(aa.z); hh[3] = (short)f2bf(aa.w);
        hh[4] = (short)f2bf(bb.x); hh[5] = (short)f2bf(bb.y);
        hh[6] = (short)f2bf(bb.z); hh[7] = (short)f2bf(bb.w);
        *(short8*)&k_ws[((long)(bq * 12 + h) * 4096 + nbase + row) * 64 + d0] = hh;
      }
    } else {
#pragma unroll
      for (int p = 0; p < 4; ++p) {
        int row = p * 4 + (lane >> 4);
        int d0 = (lane & 15) << 2;
        float4 aa = *(const float4*)&scr[row * 68 + d0];
        *(float4*)&v_out[((long)(bq * 12 + h) * 4096 + nbase + row) * 64 + d0] = aa;
      }
    }
  }
}

#undef GEMM_PROLOGUE
#undef BODY
#undef SGA
#undef SGB
#undef WBND
#undef PBAR

// ---------------------------------------------------------------------------
// Kernel 3-FALLBACK (R1 version, used when ws_size is too small)
// ---------------------------------------------------------------------------
__global__ __launch_bounds__(256) void gemm_kv(const float* __restrict__ x,
                                               const unsigned short* __restrict__ Wt,
                                               unsigned short* __restrict__ k_ws,
                                               float* __restrict__ v_out) {
  __shared__ char lds[32768];
  int bid = blockIdx.x;
  int lb = (bid & 7) * 3072 + (bid >> 3);
  int mt = lb / 12, nt = lb - mt * 12;
  long m0 = (long)mt * 128; int n0 = nt * 128;
  int tid = threadIdx.x, lane = tid & 63;
  int wid = tid >> 6, wm = wid >> 1, wn = wid & 1;
  int rlo = lane & 15, gk = lane >> 4;

  const float* xs = x + m0 * 768;
  const unsigned short* wp = Wt + (long)n0 * 768;

  int arow0 = tid >> 3, ak4 = (tid & 7) << 2;
  int bn = tid >> 1, bg = (tid & 1) << 1;

  f32x4 acc[4][4];
#pragma unroll
  for (int i = 0; i < 4; ++i)
#pragma unroll
    for (int j = 0; j < 4; ++j) acc[i][j] = (f32x4){0.f, 0.f, 0.f, 0.f};

  float4 fA[4]; short8 wB[2];
#pragma unroll
  for (int it = 0; it < 4; ++it) {
    int row = it * 32 + arow0;
    fA[it] = *(const float4*)(xs + (long)row * 768 + ak4);
  }
#pragma unroll
  for (int i = 0; i < 2; ++i)
    wB[i] = *(const short8*)(wp + (long)bn * 768 + (bg + i) * 8);
#pragma unroll
  for (int it = 0; it < 4; ++it) {
    int row = it * 32 + arow0;
    short4v h;
    h[0] = (short)f2bf(fA[it].x); h[1] = (short)f2bf(fA[it].y);
    h[2] = (short)f2bf(fA[it].z); h[3] = (short)f2bf(fA[it].w);
    *(short4v*)(lds + row * 64 + ((ak4 * 2) ^ (((row >> 1) & 3) << 4))) = h;
  }
#pragma unroll
  for (int i = 0; i < 2; ++i)
    *(short8*)(lds + 16384 + bn * 64 + (((bg + i) * 16) ^ (((bn >> 1) & 3) << 4))) = wB[i];
  __syncthreads();

#pragma unroll 2
  for (int ks = 0; ks < 24; ++ks) {
    char* Ab = lds + (ks & 1) * 8192;
    char* Bb = lds + 16384 + (ks & 1) * 8192;
    bool pf = (ks + 1 < 24);
    if (pf) {
#pragma unroll
      for (int it = 0; it < 4; ++it) {
        int row = it * 32 + arow0;
        fA[it] = *(const float4*)(xs + (long)row * 768 + (ks + 1) * 32 + ak4);
      }
#pragma unroll
      for (int i = 0; i < 2; ++i)
        wB[i] = *(const short8*)(wp + (long)bn * 768 + (ks + 1) * 32 + (bg + i) * 8);
    }
    short8 af[4], bfr[4];
#pragma unroll
    for (int mi = 0; mi < 4; ++mi) {
      int row = wm * 64 + mi * 16 + rlo;
      af[mi] = *(const short8*)(Ab + row * 64 + ((gk * 16) ^ (((row >> 1) & 3) << 4)));
    }
#pragma unroll
    for (int ni = 0; ni < 4; ++ni) {
      int n = wn * 64 + ni * 16 + rlo;
      bfr[ni] = *(const short8*)(Bb + n * 64 + ((gk * 16) ^ (((n >> 1) & 3) << 4)));
    }
#pragma unroll
    for (int mi = 0; mi < 4; ++mi)
#pragma unroll
      for (int ni = 0; ni < 4; ++ni)
        acc[mi][ni] = __builtin_amdgcn_mfma_f32_16x16x32_bf16(af[mi], bfr[ni], acc[mi][ni], 0, 0, 0);
    if (pf) {
      char* An = lds + ((ks + 1) & 1) * 8192;
      char* Bn = lds + 16384 + ((ks + 1) & 1) * 8192;
#pragma unroll
      for (int it = 0; it < 4; ++it) {
        int row = it * 32 + arow0;
        short4v h;
        h[0] = (short)f2bf(fA[it].x); h[1] = (short)f2bf(fA[it].y);
        h[2] = (short)f2bf(fA[it].z); h[3] = (short)f2bf(fA[it].w);
        *(short4v*)(An + row * 64 + ((ak4 * 2) ^ (((row >> 1) & 3) << 4))) = h;
      }
#pragma unroll
      for (int i = 0; i < 2; ++i)
        *(short8*)(Bn + bn * 64 + (((bg + i) * 16) ^ (((bn >> 1) & 3) << 4))) = wB[i];
    }
    __syncthreads();
  }

  bool is_k = (n0 < 768);
  int cb = is_k ? n0 : n0 - 768;
#pragma unroll
  for (int ni = 0; ni < 4; ++ni) {
    int cc = cb + wn * 64 + ni * 16 + rlo;
    int h = cc >> 6, d = cc & 63;
#pragma unroll
    for (int mi = 0; mi < 4; ++mi) {
#pragma unroll
      for (int r = 0; r < 4; ++r) {
        long m = m0 + wm * 64 + mi * 16 + gk * 4 + r;
        int b = (int)(m >> 12), n = (int)(m & 4095);
        long off = ((long)(b * 12 + h) * 4096 + n) * 64 + d;
        float val = acc[mi][ni][r];
        if (is_k) k_ws[off] = f2bf(val);
        else      v_out[off] = val;
      }
    }
  }
}

// ---------------------------------------------------------------------------
// Kernel 4 (R15/R17 best): fused attn, single exp pass, fp32 v loads.
// ---------------------------------------------------------------------------
__global__ __launch_bounds__(512) void attn_fused5(const unsigned short* __restrict__ k_ws,
                                                   const unsigned short* __restrict__ q_ws,
                                                   const float* __restrict__ v_glob,
                                                   float* __restrict__ attn_out,
                                                   float* __restrict__ preproj) {
  __shared__ char blob[115712];
  unsigned short* pbuf = (unsigned short*)blob;       // [8 waves][10 rows][512] bf16, swizzled
  float* part = (float*)(blob + 81920);               // [8 waves][1024] fp32
  float* redm = (float*)(blob + 114688);              // [8][16]
  float* rowmax16 = redm + 128;
  float* rowinv16 = rowmax16 + 16;

  int tid = threadIdx.x, lane = tid & 63, w = tid >> 6;
  int bh = blockIdx.x;
  int r16 = lane & 15, gk = lane >> 4;
  int trc = (r16 < 10) ? r16 : 9;
  int nW = w << 9;

  const unsigned short* kp = k_ws + (long)bh * (4096 * 64);
  const unsigned short* qp = q_ws + (long)bh * 1024;
  float* sraw = attn_out + (long)bh * 40960;
  const float* vp = v_glob + (long)bh * (4096 * 64);

  short8 qf0 = *(const short8*)(qp + r16 * 64 + gk * 8);
  short8 qf1 = *(const short8*)(qp + r16 * 64 + 32 + gk * 8);

  char* pbw = (char*)pbuf + w * 10240 + r16 * 1024;
  int swz = (r16 & 7) << 4;

  // ---- P1: QK -> masked bf16 scores to pbuf + row max ----
  float pmax = -3.0e38f;
#pragma unroll 4
  for (int ch = 0; ch < 32; ++ch) {
    int n0 = nW + (ch << 4);
    short8 kf0 = *(const short8*)(kp + (long)(n0 + r16) * 64 + gk * 8);
    short8 kf1 = *(const short8*)(kp + (long)(n0 + r16) * 64 + 32 + gk * 8);
    f32x4 d4 = (f32x4){0.f, 0.f, 0.f, 0.f};
    d4 = __builtin_amdgcn_mfma_f32_16x16x32_bf16(kf0, qf0, d4, 0, 0, 0);
    d4 = __builtin_amdgcn_mfma_f32_16x16x32_bf16(kf1, qf1, d4, 0, 0, 0);
#pragma unroll
    for (int r = 0; r < 4; ++r) {
      int n = n0 + gk * 4 + r;
      float v = d4[r];
      if (n < 10 && n != r16) v = -1e30f;
      d4[r] = v;
      pmax = fmaxf(pmax, v);
    }
    if (r16 < 10) {
      short4v h4;
      h4[0] = (short)f2bf(d4[0]); h4[1] = (short)f2bf(d4[1]);
      h4[2] = (short)f2bf(d4[2]); h4[3] = (short)f2bf(d4[3]);
      *(short4v*)(pbw + ((ch * 32 + gk * 8) ^ swz)) = h4;
    }
  }
  pmax = fmaxf(pmax, __shfl_xor(pmax, 16));
  pmax = fmaxf(pmax, __shfl_xor(pmax, 32));
  if (lane < 16) redm[w * 16 + lane] = pmax;
  __syncthreads();
  if (tid < 16) {
    float m = redm[tid];
#pragma unroll
    for (int i = 1; i < 8; ++i) m = fmaxf(m, redm[i * 16 + tid]);
    rowmax16[tid] = m;
  }
  __syncthreads();

  // ---- P2: read-back own row, exp + sum ----
  float mx = rowmax16[trc];
  char* pbr = (char*)pbuf + w * 10240 + trc * 1024;
  int swr = (trc & 7) << 4;
  float psum = 0.f;
#pragma unroll 4
  for (int i = 0; i < 16; ++i) {
    short8 sv = *(const short8*)(pbr + ((i * 64 + gk * 16) ^ swr));
#pragma unroll
    for (int j = 0; j < 8; ++j) psum += __expf(bf2f((unsigned short)sv[j]) - mx);
  }
  psum += __shfl_xor(psum, 16);
  psum += __shfl_xor(psum, 32);
  if (lane < 16) redm[w * 16 + lane] = psum;
  __syncthreads();
  if (tid < 16) {
    float t = 0.f;
#pragma unroll
    for (int i = 0; i < 8; ++i) t += redm[i * 16 + tid];
    rowinv16[tid] = 1.0f / t;
  }
  __syncthreads();
  float inv = rowinv16[trc];

  // ---- P3 (fused): p computed once -> fp32 attn write + PV A-frag ----
  f32x4 pacc[4];
#pragma unroll
  for (int dc = 0; dc < 4; ++dc) pacc[dc] = (f32x4){0.f, 0.f, 0.f, 0.f};
#pragma unroll 4
  for (int ks = 0; ks < 16; ++ks) {
    short8 raw = *(const short8*)(pbr + ((ks * 64 + gk * 16) ^ swr));
    float p0 = __expf(bf2f((unsigned short)raw[0]) - mx) * inv;
    float p1 = __expf(bf2f((unsigned short)raw[1]) - mx) * inv;
    float p2 = __expf(bf2f((unsigned short)raw[2]) - mx) * inv;
    float p3 = __expf(bf2f((unsigned short)raw[3]) - mx) * inv;
    float p4 = __expf(bf2f((unsigned short)raw[4]) - mx) * inv;
    float p5 = __expf(bf2f((unsigned short)raw[5]) - mx) * inv;
    float p6 = __expf(bf2f((unsigned short)raw[6]) - mx) * inv;
    float p7 = __expf(bf2f((unsigned short)raw[7]) - mx) * inv;
    if (r16 < 10) {                                   // pbr==pbw here: same values
      float* gp = sraw + r16 * 4096 + nW + ks * 32 + gk * 8;
      *(float4*)gp = make_float4(p0, p1, p2, p3);
      *(float4*)(gp + 4) = make_float4(p4, p5, p6, p7);
    }
    short8 pa;
    pa[0] = (short)f2bf(p0); pa[1] = (short)f2bf(p1);
    pa[2] = (short)f2bf(p2); pa[3] = (short)f2bf(p3);
    pa[4] = (short)f2bf(p4); pa[5] = (short)f2bf(p5);
    pa[6] = (short)f2bf(p6); pa[7] = (short)f2bf(p7);
    const float* vbase = vp + (long)(nW + ks * 32 + gk * 8) * 64 + r16;
#pragma unroll
    for (int dc = 0; dc < 4; ++dc) {
      short8 vb;
      const float* vrow = vbase + dc * 16;
#pragma unroll
      for (int j = 0; j < 8; ++j) vb[j] = (short)f2bf(vrow[j * 64]);
      pacc[dc] = __builtin_amdgcn_mfma_f32_16x16x32_bf16(pa, vb, pacc[dc], 0, 0, 0);
    }
  }
#pragma unroll
  for (int dc = 0; dc < 4; ++dc)
#pragma unroll
    for (int r = 0; r < 4; ++r)
      part[w * 1024 + dc * 256 + (gk * 4 + r) * 16 + r16] = pacc[dc][r];
  __syncthreads();

  // ---- P4: cross-wave reduce + preproj write ----
  int b = bh / 12, h = bh - b * 12;
  for (int idx = tid; idx < 640; idx += 512) {
    int tt = idx >> 6, d = idx & 63;
    int dc = d >> 4, dl = d & 15;
    float sum = 0.f;
#pragma unroll
    for (int i = 0; i < 8; ++i) sum += part[i * 1024 + dc * 256 + tt * 16 + dl];
    preproj[((long)b * 10 + tt) * 768 + h * 64 + d] = sum;
  }
}

// ---------------------------------------------------------------------------
// Kernel 5: x_cls = preproj @ Wp + bp
// ---------------------------------------------------------------------------
__global__ __launch_bounds__(256) void proj_out_k(const float* __restrict__ preproj,
                                                  const float* __restrict__ Wp,
                                                  const float* __restrict__ bp,
                                                  float* __restrict__ out0) {
  int b = blockIdx.x, tid = threadIdx.x;
  __shared__ float xr[7680];
  const float* pp = preproj + (long)b * 7680;
  for (int i = tid; i < 7680; i += 256) xr[i] = pp[i];
  __syncthreads();
  float acc[10][3];
#pragma unroll
  for (int t = 0; t < 10; ++t) { acc[t][0] = 0.f; acc[t][1] = 0.f; acc[t][2] = 0.f; }
  for (int k = 0; k < 768; ++k) {
    const float* wr = Wp + (long)k * 768;
    float w0 = wr[tid], w1 = wr[tid + 256], w2 = wr[tid + 512];
#pragma unroll
    for (int t = 0; t < 10; ++t) {
      float xv = xr[t * 768 + k];
      acc[t][0] += xv * w0; acc[t][1] += xv * w1; acc[t][2] += xv * w2;
    }
  }
  float b0 = bp[tid], b1 = bp[tid + 256], b2 = bp[tid + 512];
  float* op = out0 + (long)b * 7680;
#pragma unroll
  for (int t = 0; t < 10; ++t) {
    op[t * 768 + tid]       = acc[t][0] + b0;
    op[t * 768 + tid + 256] = acc[t][1] + b1;
    op[t * 768 + tid + 512] = acc[t][2] + b2;
  }
}

// ---------------------------------------------------------------------------
extern "C" void kernel_launch(void* const* d_in, const int* in_sizes, int n_in,
                              void* d_out, int out_size, void* d_ws, size_t ws_size,
                              hipStream_t stream) {
  (void)in_sizes; (void)n_in; (void)out_size;
  const float* x  = (const float*)d_in[0];
  const float* Wq = (const float*)d_in[1];
  const float* Wk = (const float*)d_in[2];
  const float* Wv = (const float*)d_in[3];
  const float* Wp = (const float*)d_in[4];
  const float* bp = (const float*)d_in[5];

  float* out      = (float*)d_out;
  float* attn_out = out + 491520;                 // [64,12,10,4096]
  float* v_out    = out + 31948800;               // [64,12,4096,64]

  char* ws = (char*)d_ws;
  const size_t NEED_BIG = 811204608;              // x_bf16 + k_ws + small (proven)

  if (ws_size >= NEED_BIG) {
    unsigned short* x_bf16 = (unsigned short*)(ws);                 // 402,653,184 B
    unsigned short* k_ws   = (unsigned short*)(ws + 402653184);     // 402,653,184 B
    unsigned short* q_ws   = (unsigned short*)(ws + 805306368);     //   1,572,864 B
    unsigned short* Wt     = (unsigned short*)(ws + 806879232);     //   2,359,296 B
    float* preproj         = (float*)(ws + 809238528);              //   1,966,080 B

    conv_x<<<dim3(2048), dim3(256), 0, stream>>>(x, x_bf16);
    prep_w<<<dim3(4608), dim3(256), 0, stream>>>(Wk, Wv, Wt);
    q_proj<<<dim3(64), dim3(256), 0, stream>>>(x, Wq, q_ws);
    gemm_kv8<<<dim3(6144), dim3(512), 0, stream>>>(x_bf16, Wt, k_ws, v_out);
    attn_fused5<<<dim3(768), dim3(512), 0, stream>>>(k_ws, q_ws, v_out, attn_out, preproj);
    proj_out_k<<<dim3(64), dim3(256), 0, stream>>>(preproj, Wp, bp, out);
  } else {
    unsigned short* k_ws = (unsigned short*)(ws);                   // 402,653,184 B
    unsigned short* q_ws = (unsigned short*)(ws + 402653184);
    unsigned short* Wt   = (unsigned short*)(ws + 404226048);
    float* preproj       = (float*)(ws + 406585344);

    prep_w<<<dim3(4608), dim3(256), 0, stream>>>(Wk, Wv, Wt);
    q_proj<<<dim3(64), dim3(256), 0, stream>>>(x, Wq, q_ws);
    gemm_kv<<<dim3(24576), dim3(256), 0, stream>>>(x, Wt, k_ws, v_out);
    attn_fused5<<<dim3(768), dim3(512), 0, stream>>>(k_ws, q_ws, v_out, attn_out, preproj);
    proj_out_k<<<dim3(64), dim3(256), 0, stream>>>(preproj, Wp, bp, out);
  }
}